// Round 7
// baseline (103.704 us; speedup 1.0000x reference)
//
#include <hip/hip_runtime.h>

// db4 decomposition low-pass
static constexpr float H0 = -0.010597401784997278f;
static constexpr float H1 =  0.032883011666982945f;
static constexpr float H2 =  0.030841381835986965f;
static constexpr float H3 = -0.18703481171888114f;
static constexpr float H4 = -0.02798376941698385f;
static constexpr float H5 =  0.6308807679295904f;
static constexpr float H6 =  0.7148465705525415f;
static constexpr float H7 =  0.23037781330885523f;

// Correlation weights, per-level 0.5 folded in (exact pow2 scale).
static constexpr float W0[8] = { 0.5f*H0,  0.5f*H1,  0.5f*H2,  0.5f*H3,
                                 0.5f*H4,  0.5f*H5,  0.5f*H6,  0.5f*H7 };
static constexpr float W1[8] = {-0.5f*H7,  0.5f*H6, -0.5f*H5,  0.5f*H4,
                                -0.5f*H3,  0.5f*H2, -0.5f*H1,  0.5f*H0 };

constexpr int T  = 4096;
constexpr int BD = 2112;   // staged dwords per band = 528 granules ([g0-7, g0+521])
constexpr int NT = 4;      // tiles per block (2 rows: 2 tiles/row)

// One inverse level, one output granule lg (4 floats), linear band buffers.
// out[4lg+jp] = sum_k W0[k]*LO[4(lg-D)+jp+D*k] + W1[k]*HI[...]; window [lg-D, lg-D+NG).
template <int D, int NG>
static __device__ __forceinline__ void lvl(const float* __restrict__ lo,
                                           const float* __restrict__ hi,
                                           int lg, float r[4])
{
    float wl[NG * 4], wh[NG * 4];
#pragma unroll
    for (int j = 0; j < NG; ++j) {
        const float4 vl = *(const float4*)(lo + 4 * (lg - D + j));
        const float4 vh = *(const float4*)(hi + 4 * (lg - D + j));
        wl[4*j+0] = vl.x; wl[4*j+1] = vl.y; wl[4*j+2] = vl.z; wl[4*j+3] = vl.w;
        wh[4*j+0] = vh.x; wh[4*j+1] = vh.y; wh[4*j+2] = vh.z; wh[4*j+3] = vh.w;
    }
#pragma unroll
    for (int jp = 0; jp < 4; ++jp) {
        float a = 0.0f;
#pragma unroll
        for (int k = 0; k < 8; ++k) {
            a = fmaf(W0[k], wl[jp + D * k], a);
            a = fmaf(W1[k], wh[jp + D * k], a);
        }
        r[jp] = a;
    }
}

static __device__ __forceinline__ void st4(float* __restrict__ p, const float r[4])
{ *(float4*)p = make_float4(r[0], r[1], r[2], r[3]); }

__global__ __launch_bounds__(256, 2)
void iswt_kernel(const float* __restrict__ in, float* __restrict__ out)
{
    // band layout: 0=cA_3, 1=cD_3, 2=cD_2, 3=cD_1 (matches input float4 components)
    __shared__ __align__(16) float bands[2][4][BD];   // 67.5 KB (double-buffered DMA target)
    __shared__ __align__(16) float S[BD];             // r1 spare, 8.25 KB

    const int t    = threadIdx.x;
    const int wv   = t >> 6;      // wave stages band wv
    const int lane = t & 63;
    const int tile0 = blockIdx.x * NT;

    // Width-4 DMA: lane reads band wv at position p -> lands at lane-consecutive
    // dwords (deinterleave in the DMA). 33 chunks x 64 positions = 2112 dwords.
    auto issue = [&](int set, int tile) {
        const int row = tile >> 1;
        const int t0  = (tile & 1) << 11;
        const float* rb = in + (size_t)row * (T * 4);
        for (int c = 0; c < 33; ++c) {
            const int p = (t0 - 28 + (c << 6) + lane) & (T - 1);   // per-lane src, wrap ok
            __builtin_amdgcn_global_load_lds(
                (const __attribute__((address_space(1))) void*)(rb + 4 * p + wv),
                (__attribute__((address_space(3))) void*)(&bands[set][wv][c << 6]),
                4, 0, 0);
        }
    };

    issue(0, tile0);
    int cur = 0;

    for (int i = 0; i < NT; ++i) {
        const int tile = tile0 + i;
        const int row  = tile >> 1;
        const int t0   = (tile & 1) << 11;

        if (i + 1 < NT) {
            issue(cur ^ 1, tile + 1);                       // next tile's DMA: in flight under compute
            asm volatile("s_waitcnt vmcnt(33)" ::: "memory");  // wait ONLY current set (+older)
        } else {
            asm volatile("s_waitcnt vmcnt(0)" ::: "memory");
        }
        __builtin_amdgcn_s_barrier();                       // all 4 bands of cur visible

        const float* cA  = bands[cur][0];
        const float* cD3 = bands[cur][1];
        const float* cD2 = bands[cur][2];
        float*       cD1 = bands[cur][3];
        float r[4];

        // ---- Level 1: lo=cD1, hi=cD2, D=4 -> S over granules [4,522) ----
        lvl<4, 8>(cD1, cD2, 4 + t, r);    st4(S + 4 * (4 + t), r);
        lvl<4, 8>(cD1, cD2, 260 + t, r);  st4(S + 4 * (260 + t), r);
        if (t < 6) { lvl<4, 8>(cD1, cD2, 516 + t, r); st4(S + 4 * (516 + t), r); }
        asm volatile("s_waitcnt lgkmcnt(0)" ::: "memory");  // LDS only: DMAs stay in flight
        __builtin_amdgcn_s_barrier();

        // ---- Level 2: lo=S(r1), hi=cD3, D=2 -> cD1 (dead) over [6,520) ----
        lvl<2, 5>(S, cD3, 6 + t, r);      st4(cD1 + 4 * (6 + t), r);
        lvl<2, 5>(S, cD3, 262 + t, r);    st4(cD1 + 4 * (262 + t), r);
        if (t < 2) { lvl<2, 5>(S, cD3, 518 + t, r); st4(cD1 + 4 * (518 + t), r); }
        asm volatile("s_waitcnt lgkmcnt(0)" ::: "memory");
        __builtin_amdgcn_s_barrier();

        // ---- Level 3: lo=cD1(r2), hi=cA, D=1, granules [7,519) -> global ----
        float* orow = out + (size_t)row * T + t0;
        lvl<1, 3>(cD1, cA, 7 + t, r);     st4(orow + 4 * t, r);
        lvl<1, 3>(cD1, cA, 263 + t, r);   st4(orow + 1024 + 4 * t, r);
        asm volatile("s_waitcnt lgkmcnt(0)" ::: "memory");  // cur-set reads complete
        __builtin_amdgcn_s_barrier();                       // safe to re-DMA cur next iter

        cur ^= 1;
    }
}

extern "C" void kernel_launch(void* const* d_in, const int* in_sizes, int n_in,
                              void* d_out, int out_size, void* d_ws, size_t ws_size,
                              hipStream_t stream)
{
    const float* coeffs = (const float*)d_in[0];
    float* out = (float*)d_out;
    const int nrows  = in_sizes[0] / (T * 4);   // 4096
    const int blocks = nrows * 2 / NT;          // 8192 tiles / 4 = 2048
    iswt_kernel<<<blocks, 256, 0, stream>>>(coeffs, out);
}

// Round 9
// 93.128 us; speedup vs baseline: 1.1136x; 1.1136x over previous
//
#include <hip/hip_runtime.h>

// db4 decomposition low-pass
static constexpr float H0 = -0.010597401784997278f;
static constexpr float H1 =  0.032883011666982945f;
static constexpr float H2 =  0.030841381835986965f;
static constexpr float H3 = -0.18703481171888114f;
static constexpr float H4 = -0.02798376941698385f;
static constexpr float H5 =  0.6308807679295904f;
static constexpr float H6 =  0.7148465705525415f;
static constexpr float H7 =  0.23037781330885523f;

// Correlation weights with the per-level 0.5 folded in (exact: *0.5 is a pow2 scale).
static constexpr float W0[8] = { 0.5f*H0,  0.5f*H1,  0.5f*H2,  0.5f*H3,
                                 0.5f*H4,  0.5f*H5,  0.5f*H6,  0.5f*H7 };
static constexpr float W1[8] = {-0.5f*H7,  0.5f*H6, -0.5f*H5,  0.5f*H4,
                                -0.5f*H3,  0.5f*H2, -0.5f*H1,  0.5f*H0 };

constexpr int T      = 4096;   // time length per row
constexpr int GMASK  = 1023;   // granule count per row (T/4) - 1
constexpr int BANDF  = 5120;   // padded floats per band: 1024 granules + 1 pad granule per 4

typedef float floatx4 __attribute__((ext_vector_type(4)));   // native vector for nt-store

// padded float index of granule g (pad one 4-float granule every 4 granules)
static __device__ __forceinline__ int gaddr(int g) { return (g << 2) + ((g >> 2) << 2); }

// One inverse-SWT level: each thread produces 16 consecutive outputs from its
// register halo window.  out[i] = sum_k W0[k]*LO[i + D*k] + W1[k]*HI[i + D*k],
// window starting at granule g0 - D.
template <int D, int NG>
static __device__ __forceinline__ void level(const float* __restrict__ lo_buf,
                                             const float* __restrict__ hi_buf,
                                             int g0, float res[16])
{
    float wl[NG * 4], wh[NG * 4];
#pragma unroll
    for (int j = 0; j < NG; ++j) {
        const int g = (g0 - D + j) & GMASK;
        const int a = gaddr(g);
        const float4 vl = *(const float4*)(lo_buf + a);
        const float4 vh = *(const float4*)(hi_buf + a);
        wl[4 * j + 0] = vl.x; wl[4 * j + 1] = vl.y; wl[4 * j + 2] = vl.z; wl[4 * j + 3] = vl.w;
        wh[4 * j + 0] = vh.x; wh[4 * j + 1] = vh.y; wh[4 * j + 2] = vh.z; wh[4 * j + 3] = vh.w;
    }
#pragma unroll
    for (int i = 0; i < 16; ++i) {
        float acc = 0.0f;
#pragma unroll
        for (int k = 0; k < 8; ++k) {
            acc = fmaf(W0[k], wl[i + D * k], acc);
            acc = fmaf(W1[k], wh[i + D * k], acc);
        }
        res[i] = acc;
    }
}

static __device__ __forceinline__ void writeback(float* __restrict__ dst, int g0,
                                                 const float res[16])
{
#pragma unroll
    for (int j = 0; j < 4; ++j) {
        const int a = gaddr(g0 + j);
        *(float4*)(dst + a) = make_float4(res[4 * j + 0], res[4 * j + 1],
                                          res[4 * j + 2], res[4 * j + 3]);
    }
}

__global__ __launch_bounds__(256, 2)
void iswt_kernel(const float* __restrict__ in, float* __restrict__ out)
{
    __shared__ float lds[4][BANDF];   // 4 bands, 20 KB each = 80 KB

    const int row = blockIdx.x;
    const int tid = threadIdx.x;

    // ---- stage: deinterleave the 4 bands (coalesced float4 loads) ----
    const float4* __restrict__ src = (const float4*)(in + (size_t)row * (T * 4));
#pragma unroll
    for (int j = 0; j < 16; ++j) {
        const int p = tid + 256 * j;          // position in row
        const float4 v = src[p];              // (band0, band1, band2, band3) at p
        const int a = p + ((p >> 4) << 2);    // padded scalar float index
        lds[0][a] = v.x;   // cA_3
        lds[1][a] = v.y;   // cD_3
        lds[2][a] = v.z;   // cD_2
        lds[3][a] = v.w;   // cD_1
    }
    __syncthreads();

    const int g0 = tid << 2;   // base granule of this thread's 16-output chunk
    float res[16];

    // Level 1: lo = band3 (cD_1), hi = band2 (cD_2), dilation 4
    level<4, 11>(&lds[3][0], &lds[2][0], g0, res);
    __syncthreads();
    writeback(&lds[3][0], g0, res);           // band3/band2 dead -> reuse buf3
    __syncthreads();

    // Level 2: lo = res (buf3), hi = band1 (cD_3), dilation 2
    level<2, 8>(&lds[3][0], &lds[1][0], g0, res);
    __syncthreads();
    writeback(&lds[1][0], g0, res);           // reuse buf1
    __syncthreads();

    // Level 3: lo = res (buf1), hi = band0 (cA_3), dilation 1 -> global
    level<1, 6>(&lds[1][0], &lds[0][0], g0, res);

    // Non-temporal stores: output is write-once/never-read -> don't allocate in
    // L2/L3, keep the LLC for the (exactly L3-sized) input across graph replays.
    float* __restrict__ o = out + (size_t)row * T + (tid << 4);
#pragma unroll
    for (int j = 0; j < 4; ++j) {
        floatx4 v;
        v.x = res[4 * j + 0]; v.y = res[4 * j + 1];
        v.z = res[4 * j + 2]; v.w = res[4 * j + 3];
        __builtin_nontemporal_store(v, (floatx4*)(o + 4 * j));
    }
}

extern "C" void kernel_launch(void* const* d_in, const int* in_sizes, int n_in,
                              void* d_out, int out_size, void* d_ws, size_t ws_size,
                              hipStream_t stream)
{
    const float* coeffs = (const float*)d_in[0];
    float* out = (float*)d_out;
    const int nrows = in_sizes[0] / (T * 4);   // B*N = 4096
    iswt_kernel<<<nrows, 256, 0, stream>>>(coeffs, out);
}